// Round 11
// baseline (86880.133 us; speedup 1.0000x reference)
//
#include <hip/hip_runtime.h>
#include <stdint.h>
#include <math.h>

#pragma clang fp contract(off)

#define BATCH 64
#define HID   1024
#define EMBD  512
#define VOC   32000
#define MAXT  64
#define NTOPK 60
#define CAND_MAX 256
#define NB    512   // 2 blocks/CU co-resident; LDS ~10KB, launch_bounds(256,2)

// ---------------- XLA-CPU math replicas ----------------
__device__ __forceinline__ float xla_tanh(float x) {
  float ax = fabsf(x);
  float xc = fminf(fmaxf(x, -9.0f), 9.0f);
  float x2 = xc * xc;
  float num = -2.76076847742355e-16f;
  num = fmaf(x2, num, 2.00018790482477e-13f);
  num = fmaf(x2, num, -8.60467152213735e-11f);
  num = fmaf(x2, num, 5.12229709037114e-08f);
  num = fmaf(x2, num, 1.48572235717979e-05f);
  num = fmaf(x2, num, 6.37261928875436e-04f);
  num = fmaf(x2, num, 4.89352455891786e-03f);
  num = xc * num;
  float den = 1.19825839466702e-06f;
  den = fmaf(x2, den, 1.18534705686654e-04f);
  den = fmaf(x2, den, 2.26843463243900e-03f);
  den = fmaf(x2, den, 4.89352518554385e-03f);
  float r = num / den;
  return (ax < 0.0004f) ? x : r;
}

__device__ __forceinline__ float xla_sigmoid(float x) {
  return 0.5f * xla_tanh(0.5f * x) + 0.5f;
}

// Eigen/XLA pexp<float>
__device__ __forceinline__ float cephes_expf(float _x) {
  float x = fminf(_x, 88.723164f);
  x = fmaxf(x, -88.723164f);
  float m = floorf(fmaf(x, 1.44269504088896341f, 0.5f));
  float r = fmaf(m, -0.693359375f, x);
  r = fmaf(m, 2.12194440e-4f, r);
  float r2 = r * r;
  float r3 = r2 * r;
  float y, y1, y2;
  y  = fmaf(1.9875691500E-4f, r, 1.3981999507E-3f);
  y1 = fmaf(4.1665795894E-2f, r, 1.6666665459E-1f);
  y2 = r + 1.0f;
  y  = fmaf(y, r, 8.3334519073E-3f);
  y1 = fmaf(y1, r, 5.0000001201E-1f);
  y  = fmaf(y, r3, y1);
  y  = fmaf(y, r2, y2);
  float res = ldexpf(y, (int)m);
  return fmaxf(res, _x);
}

// Cephes/XLA plog
__device__ __forceinline__ float cephes_logf(float _x) {
  float x = fmaxf(_x, 1.17549435e-38f);
  unsigned ux = __float_as_uint(x);
  int e_int = (int)(ux >> 23) - 126;
  x = __uint_as_float((ux & 0x007FFFFFu) | 0x3F000000u);
  float e = (float)e_int;
  if (x < 0.707106781186547524f) { e -= 1.0f; x = x + x - 1.0f; }
  else { x = x - 1.0f; }
  float z = x * x;
  float y = 7.0376836292E-2f;
  y = fmaf(y, x, -1.1514610310E-1f);
  y = fmaf(y, x,  1.1676998740E-1f);
  y = fmaf(y, x, -1.2420140846E-1f);
  y = fmaf(y, x,  1.4249322787E-1f);
  y = fmaf(y, x, -1.6668057665E-1f);
  y = fmaf(y, x,  2.0000714765E-1f);
  y = fmaf(y, x, -2.4999993993E-1f);
  y = fmaf(y, x,  3.3333331174E-1f);
  y = y * x;
  y = y * z;
  y = fmaf(e, -2.12194440e-4f, y);
  y = fmaf(-0.5f, z, y);
  float r = x + y;
  r = fmaf(e, 0.693359375f, r);
  return r;
}

// ---------------- threefry2x32 (exact) ----------------
__device__ __forceinline__ unsigned rotl32(unsigned v, int s) {
  return (v << s) | (v >> (32 - s));
}
__device__ __forceinline__ void threefry(unsigned k0, unsigned k1,
                                         unsigned& x0, unsigned& x1) {
  unsigned k2 = k0 ^ k1 ^ 0x1BD11BDAu;
  x0 += k0; x1 += k1;
  x0 += x1; x1 = rotl32(x1, 13); x1 ^= x0;
  x0 += x1; x1 = rotl32(x1, 15); x1 ^= x0;
  x0 += x1; x1 = rotl32(x1, 26); x1 ^= x0;
  x0 += x1; x1 = rotl32(x1,  6); x1 ^= x0;
  x0 += k1; x1 += k2 + 1u;
  x0 += x1; x1 = rotl32(x1, 17); x1 ^= x0;
  x0 += x1; x1 = rotl32(x1, 29); x1 ^= x0;
  x0 += x1; x1 = rotl32(x1, 16); x1 ^= x0;
  x0 += x1; x1 = rotl32(x1, 24); x1 ^= x0;
  x0 += k2; x1 += k0 + 2u;
  x0 += x1; x1 = rotl32(x1, 13); x1 ^= x0;
  x0 += x1; x1 = rotl32(x1, 15); x1 ^= x0;
  x0 += x1; x1 = rotl32(x1, 26); x1 ^= x0;
  x0 += x1; x1 = rotl32(x1,  6); x1 ^= x0;
  x0 += k0; x1 += k1 + 3u;
  x0 += x1; x1 = rotl32(x1, 17); x1 ^= x0;
  x0 += x1; x1 = rotl32(x1, 29); x1 ^= x0;
  x0 += x1; x1 = rotl32(x1, 16); x1 ^= x0;
  x0 += x1; x1 = rotl32(x1, 24); x1 ^= x0;
  x0 += k1; x1 += k2 + 4u;
  x0 += x1; x1 = rotl32(x1, 13); x1 ^= x0;
  x0 += x1; x1 = rotl32(x1, 15); x1 ^= x0;
  x0 += x1; x1 = rotl32(x1, 26); x1 ^= x0;
  x0 += x1; x1 = rotl32(x1,  6); x1 ^= x0;
  x0 += k2; x1 += k0 + 5u;
}

__device__ __forceinline__ float gumbel_val(unsigned k0, unsigned k1, int b, int v) {
  unsigned x0 = 0u, x1 = (unsigned)(b * VOC + v);
  threefry(k0, k1, x0, x1);
  unsigned bits = x0 ^ x1;
  float u = __uint_as_float(0x3f800000u | (bits >> 9)) - 1.0f;
  if (u == 0.0f) u = 1.17549435e-38f;
  return -cephes_logf(-cephes_logf(u));
}

__device__ __forceinline__ unsigned okey(float f) {
  unsigned u = __float_as_uint(f);
  return (u & 0x80000000u) ? ~u : (u | 0x80000000u);
}

// ---- agent-scope (sc1, L2-bypass) store: workspace writes never dirty L2 ----
template <typename T>
__device__ __forceinline__ void st_dev(T* p, T v) {
  __hip_atomic_store(p, v, __ATOMIC_RELAXED, __HIP_MEMORY_SCOPE_AGENT);
}

// ---- grid barrier v2: drain stores (already at LLC via sc1) -> arrive ->
//      spin -> acquire fence (buffer_inv only; no dirty lines -> no wbl2) ----
__device__ __forceinline__ void gbar(unsigned* cnt, unsigned target) {
  asm volatile("s_waitcnt vmcnt(0) lgkmcnt(0)" ::: "memory");
  __syncthreads();
  if (threadIdx.x == 0) {
    __hip_atomic_fetch_add(cnt, 1u, __ATOMIC_RELAXED, __HIP_MEMORY_SCOPE_AGENT);
    while (__hip_atomic_load(cnt, __ATOMIC_RELAXED, __HIP_MEMORY_SCOPE_AGENT) < target)
      __builtin_amdgcn_s_sleep(16);
  }
  __syncthreads();
  __builtin_amdgcn_fence(__ATOMIC_ACQUIRE, "agent");  // invalidate stale L1/L2
}

// ---------------- the whole decoder in one kernel ----------------
__global__ __launch_bounds__(256, 2) void k_mega(
    const float* __restrict__ thought, const float* __restrict__ emb,
    const float* __restrict__ w_ih0, const float* __restrict__ b_ih0,
    const float* __restrict__ w_hh0, const float* __restrict__ b_hh0,
    const float* __restrict__ w_ih1, const float* __restrict__ b_ih1,
    const float* __restrict__ w_hh1, const float* __restrict__ b_hh1,
    const float* __restrict__ gw1, const float* __restrict__ gb1,
    const float* __restrict__ gw2, const float* __restrict__ gb2,
    const float* __restrict__ out_w, const float* __restrict__ out_b,
    float* h1a, float* h1b, float* h2a, float* h2b, float* c1, float* c2,
    float* prev_ctx, float* gtmp, float* counts, float* raw, float* adj,
    int* word, int* hist, int* out_tokens, unsigned* bar) {

  __shared__ float sg[2][4][64];     // gates scratch (2 KB)
  __shared__ float red[256];
  __shared__ float gshv;
  __shared__ int wcnt4[4];
  __shared__ int sh_cnt;
  __shared__ float cval[CAND_MAX];
  __shared__ int cidx[CAND_MAX];
  __shared__ float sval[CAND_MAX];
  __shared__ int sidx[CAND_MAX];
  __shared__ unsigned char kept[CAND_MAX];
  __shared__ float rval[256];
  __shared__ int ridx[256];
  __shared__ unsigned shk0, shk1;
  __shared__ int hcol[MAXT];
  __shared__ float wtab[MAXT];

  const int blk = blockIdx.x, tid = threadIdx.x;
  unsigned bt = 0;

  // ---- phase 0: init (grid-stride, sc-stores) ----
  for (int i = blk * 256 + tid; i < BATCH * HID; i += NB * 256) {
    float tv = thought[i];
    st_dev(&h1a[i], tv); st_dev(&h2a[i], tv); st_dev(&prev_ctx[i], tv);
    st_dev(&c1[i], 0.f); st_dev(&c2[i], 0.f);
  }
  for (int i = blk * 256 + tid; i < VOC; i += NB * 256) st_dev(&counts[i], 0.f);
  for (int i = blk * 256 + tid; i < MAXT * BATCH; i += NB * 256) st_dev(&hist[i], 0);
  for (int i = blk * 256 + tid; i < BATCH; i += NB * 256) st_dev(&word[i], 1);
  gbar(bar, (++bt) * NB);

  for (int t = 0; t < MAXT; ++t) {
    const float* h1r = (t & 1) ? h1b : h1a;
    float*       h1w = (t & 1) ? h1a : h1b;
    const float* h2r = (t & 1) ? h2b : h2a;
    float*       h2w = (t & 1) ? h2a : h2b;

    // ---- phase A: layer-0 gates + fused cell (block = u-pair) ----
    {
      int gate = tid & 3, b = tid >> 2;
      int u0 = blk * 2;
      int j0 = gate * 1024 + u0, j1 = j0 + 1;
      const float4* wi0 = (const float4*)(w_ih0 + (size_t)j0 * (EMBD + HID));
      const float4* wi1 = (const float4*)(w_ih0 + (size_t)j1 * (EMBD + HID));
      const float4* wh0 = (const float4*)(w_hh0 + (size_t)j0 * HID);
      const float4* wh1 = (const float4*)(w_hh0 + (size_t)j1 * HID);
      const float4* e4 = (const float4*)(emb + (size_t)word[b] * EMBD);
      const float4* p4 = (const float4*)(prev_ctx + (size_t)b * HID);
      const float4* h4 = (const float4*)(h1r + (size_t)b * HID);
      float acc0 = 0.f, acc1 = 0.f, shh0 = 0.f, shh1 = 0.f;
      for (int k = 0; k < EMBD / 4; ++k) {
        float4 a = e4[k];
        float4 w = wi0[k];
        acc0 = fmaf(a.x, w.x, acc0); acc0 = fmaf(a.y, w.y, acc0);
        acc0 = fmaf(a.z, w.z, acc0); acc0 = fmaf(a.w, w.w, acc0);
        w = wi1[k];
        acc1 = fmaf(a.x, w.x, acc1); acc1 = fmaf(a.y, w.y, acc1);
        acc1 = fmaf(a.z, w.z, acc1); acc1 = fmaf(a.w, w.w, acc1);
      }
      for (int k = 0; k < HID / 4; ++k) {
        float4 a = p4[k];
        float4 w = wi0[EMBD / 4 + k];
        acc0 = fmaf(a.x, w.x, acc0); acc0 = fmaf(a.y, w.y, acc0);
        acc0 = fmaf(a.z, w.z, acc0); acc0 = fmaf(a.w, w.w, acc0);
        w = wi1[EMBD / 4 + k];
        acc1 = fmaf(a.x, w.x, acc1); acc1 = fmaf(a.y, w.y, acc1);
        acc1 = fmaf(a.z, w.z, acc1); acc1 = fmaf(a.w, w.w, acc1);
      }
      for (int k = 0; k < HID / 4; ++k) {
        float4 a = h4[k];
        float4 w = wh0[k];
        shh0 = fmaf(a.x, w.x, shh0); shh0 = fmaf(a.y, w.y, shh0);
        shh0 = fmaf(a.z, w.z, shh0); shh0 = fmaf(a.w, w.w, shh0);
        w = wh1[k];
        shh1 = fmaf(a.x, w.x, shh1); shh1 = fmaf(a.y, w.y, shh1);
        shh1 = fmaf(a.z, w.z, shh1); shh1 = fmaf(a.w, w.w, shh1);
      }
      sg[0][gate][b] = ((acc0 + b_ih0[j0]) + shh0) + b_hh0[j0];
      sg[1][gate][b] = ((acc1 + b_ih0[j1]) + shh1) + b_hh0[j1];
      __syncthreads();
      if (tid < 128) {
        int us = tid >> 6, b2 = tid & 63;
        int uu = u0 + us;
        float iv = sg[us][0][b2], fv = sg[us][1][b2], gv = sg[us][2][b2], ov = sg[us][3][b2];
        size_t idx = (size_t)b2 * HID + uu;
        float cold = c1[idx];
        float cnew = xla_sigmoid(fv) * cold + xla_sigmoid(iv) * xla_tanh(gv);
        st_dev(&c1[idx], cnew);
        st_dev(&h1w[idx], xla_sigmoid(ov) * xla_tanh(cnew));
      }
    }
    gbar(bar, (++bt) * NB);

    // ---- phase B: layer-1 gates + fused cell ----
    {
      int gate = tid & 3, b = tid >> 2;
      int u0 = blk * 2;
      int j0 = gate * 1024 + u0, j1 = j0 + 1;
      const float4* wi0 = (const float4*)(w_ih1 + (size_t)j0 * HID);
      const float4* wi1 = (const float4*)(w_ih1 + (size_t)j1 * HID);
      const float4* wh0 = (const float4*)(w_hh1 + (size_t)j0 * HID);
      const float4* wh1 = (const float4*)(w_hh1 + (size_t)j1 * HID);
      const float4* x4 = (const float4*)(h1w + (size_t)b * HID);
      const float4* h4 = (const float4*)(h2r + (size_t)b * HID);
      float acc0 = 0.f, acc1 = 0.f, shh0 = 0.f, shh1 = 0.f;
      for (int k = 0; k < HID / 4; ++k) {
        float4 a = x4[k];
        float4 w = wi0[k];
        acc0 = fmaf(a.x, w.x, acc0); acc0 = fmaf(a.y, w.y, acc0);
        acc0 = fmaf(a.z, w.z, acc0); acc0 = fmaf(a.w, w.w, acc0);
        w = wi1[k];
        acc1 = fmaf(a.x, w.x, acc1); acc1 = fmaf(a.y, w.y, acc1);
        acc1 = fmaf(a.z, w.z, acc1); acc1 = fmaf(a.w, w.w, acc1);
      }
      for (int k = 0; k < HID / 4; ++k) {
        float4 a = h4[k];
        float4 w = wh0[k];
        shh0 = fmaf(a.x, w.x, shh0); shh0 = fmaf(a.y, w.y, shh0);
        shh0 = fmaf(a.z, w.z, shh0); shh0 = fmaf(a.w, w.w, shh0);
        w = wh1[k];
        shh1 = fmaf(a.x, w.x, shh1); shh1 = fmaf(a.y, w.y, shh1);
        shh1 = fmaf(a.z, w.z, shh1); shh1 = fmaf(a.w, w.w, shh1);
      }
      sg[0][gate][b] = ((acc0 + b_ih1[j0]) + shh0) + b_hh1[j0];
      sg[1][gate][b] = ((acc1 + b_ih1[j1]) + shh1) + b_hh1[j1];
      __syncthreads();
      if (tid < 128) {
        int us = tid >> 6, b2 = tid & 63;
        int uu = u0 + us;
        float iv = sg[us][0][b2], fv = sg[us][1][b2], gv = sg[us][2][b2], ov = sg[us][3][b2];
        size_t idx = (size_t)b2 * HID + uu;
        float cold = c2[idx];
        float cnew = xla_sigmoid(fv) * cold + xla_sigmoid(iv) * xla_tanh(gv);
        st_dev(&c2[idx], cnew);
        st_dev(&h2w[idx], xla_sigmoid(ov) * xla_tanh(cnew));
      }
    }
    gbar(bar, (++bt) * NB);

    // ---- phase C1: gtmp = tanh(h2 @ gw1^T + gb1), 256 blocks x (4u, 64b) ----
    if (blk < 256) {
      int ul = tid & 3, b = tid >> 2;
      int u = blk * 4 + ul;
      const float4* w4 = (const float4*)(gw1 + (size_t)u * HID);
      const float4* a4 = (const float4*)(h2w + (size_t)b * HID);
      float acc = 0.f;
      for (int k = 0; k < HID / 4; ++k) {
        float4 w = w4[k];
        float4 a = a4[k];
        acc = fmaf(a.x, w.x, acc); acc = fmaf(a.y, w.y, acc);
        acc = fmaf(a.z, w.z, acc); acc = fmaf(a.w, w.w, acc);
      }
      st_dev(&gtmp[(size_t)b * HID + u], xla_tanh(acc + gb1[u]));
    }
    gbar(bar, (++bt) * NB);

    // ---- phase C2: gate = sigmoid(gtmp @ gw2^T + gb2); prev_ctx = h2*gate ----
    if (blk < BATCH) {
      int b = blk;
      float s = 0.f;
      for (int k = tid; k < HID; k += 256)
        s = fmaf(gtmp[(size_t)b * HID + k], gw2[k], s);
      red[tid] = s;
      __syncthreads();
      for (int st = 128; st > 0; st >>= 1) {
        if (tid < st) red[tid] += red[tid + st];
        __syncthreads();
      }
      if (tid == 0) gshv = xla_sigmoid(red[0] + gb2[0]);
      __syncthreads();
      float gate = gshv;
      for (int k = tid; k < HID; k += 256)
        st_dev(&prev_ctx[(size_t)b * HID + k], h2w[(size_t)b * HID + k] * gate);
    }
    gbar(bar, (++bt) * NB);

    // ---- phase D: logits, 500 chunks of 64 v, 1 chunk per block ----
    if (blk < 500) {
      int lz;
      asm volatile("v_mov_b32 %0, 0" : "=v"(lz));   // opaque 0: forces vector loads
      int vl = tid & 63;
      int bbase = (tid >> 6) * 16;
      const float4* ap = (const float4*)(prev_ctx + (size_t)bbase * HID + lz);
      int v = blk * 64 + vl;
      const float4* w4 = (const float4*)(out_w + (size_t)v * HID);
      float acc[16];
      #pragma unroll
      for (int i = 0; i < 16; ++i) acc[i] = 0.f;
      for (int k = 0; k < HID / 4; ++k) {
        float4 w = w4[k];
        #pragma unroll
        for (int i = 0; i < 16; ++i) {
          float4 a = ap[k + 256 * i];
          acc[i] = fmaf(a.x, w.x, acc[i]); acc[i] = fmaf(a.y, w.y, acc[i]);
          acc[i] = fmaf(a.z, w.z, acc[i]); acc[i] = fmaf(a.w, w.w, acc[i]);
        }
      }
      float c = counts[v];
      float cpen = (c > 1.0f) ? (2.0f * c) : 0.0f;
      float bonus = 0.3f / (c + 1.0f);
      float bv = out_b[v];
      #pragma unroll
      for (int i = 0; i < 16; ++i) {
        int b = bbase + i;
        float r = acc[i] + bv;
        st_dev(&raw[(size_t)b * VOC + v], r);
        st_dev(&adj[(size_t)b * VOC + v], (r - cpen) / 0.9f + bonus);
      }
    }
    gbar(bar, (++bt) * NB);

    // ---- phase E: penfix + top-k (global binary search) + nucleus + gumbel ----
    if (blk < BATCH) {
      int b = blk;
      float* row = adj + (size_t)b * VOC;

      if (tid < t) hcol[tid] = hist[tid * BATCH + b];
      if (tid < MAXT) wtab[tid] = 2.5f * powf(0.8f, (float)tid);
      if (tid == 0) {
        sh_cnt = 0;
        unsigned a = 0u, cc = (unsigned)t;
        threefry(0u, 42u, a, cc);
        shk0 = a; shk1 = cc;
      }
      __syncthreads();

      // penfix (ascending a2 order == reference scatter-add order)
      if (tid < t) {
        int ar = tid;
        int tok = hcol[ar];
        bool first = true;
        for (int a2 = 0; a2 < ar; ++a2)
          if (hcol[a2] == tok) { first = false; break; }
        if (first) {
          float pen = 0.f;
          for (int a2 = ar; a2 < t; ++a2)
            if (hcol[a2] == tok) pen += wtab[t - a2];
          float c = counts[tok];
          float cpen = (c > 1.0f) ? (2.0f * c) : 0.0f;
          float bonus = 0.3f / (c + 1.0f);
          float r = raw[(size_t)b * VOC + tok];
          st_dev(&row[tok], ((r - pen) - cpen) / 0.9f + bonus);
        }
      }
      asm volatile("s_waitcnt vmcnt(0) lgkmcnt(0)" ::: "memory");  // drain sc-store
      __syncthreads();

      // binary search for kmin = max T with count(okey(row) >= T) >= NTOPK
      const float4* row4 = (const float4*)row;
      unsigned long long lo = 0ULL, hi = 1ULL << 32;
      for (int it = 0; it < 32; ++it) {
        unsigned mid = (unsigned)((lo + hi) >> 1);
        int cnt = 0;
        for (int i = tid; i < VOC / 4; i += 256) {
          float4 f = row4[i];
          cnt += (okey(f.x) >= mid) ? 1 : 0;
          cnt += (okey(f.y) >= mid) ? 1 : 0;
          cnt += (okey(f.z) >= mid) ? 1 : 0;
          cnt += (okey(f.w) >= mid) ? 1 : 0;
        }
        #pragma unroll
        for (int off = 32; off > 0; off >>= 1)
          cnt += __shfl_xor(cnt, off, 64);
        if ((tid & 63) == 0) wcnt4[tid >> 6] = cnt;
        __syncthreads();
        int total = wcnt4[0] + wcnt4[1] + wcnt4[2] + wcnt4[3];
        if (total >= NTOPK) lo = (unsigned long long)mid;
        else                hi = (unsigned long long)mid;
        __syncthreads();
      }
      unsigned kmin = (unsigned)lo;

      // gather candidates (key >= kmin keeps ties, like reference)
      for (int v = tid; v < VOC; v += 256) {
        float f = row[v];
        if (okey(f) >= kmin) {
          int pos = atomicAdd(&sh_cnt, 1);
          if (pos < CAND_MAX) { cval[pos] = f; cidx[pos] = v; }
        }
      }
      __syncthreads();
      int C = sh_cnt; if (C > CAND_MAX) C = CAND_MAX;

      // stable sort (value desc, index asc) via rank
      for (int i = tid; i < C; i += 256) {
        float vi = cval[i]; int ii = cidx[i]; int r = 0;
        for (int j = 0; j < C; ++j) {
          float vj = cval[j]; int ij = cidx[j];
          if (vj > vi || (vj == vi && ij < ii)) ++r;
        }
        sval[r] = vi; sidx[r] = ii;
      }
      __syncthreads();

      // softmax + cumsum nucleus (sequential f32, thread 0)
      if (tid == 0) {
        float m = sval[0];
        float psum = 0.f;
        for (int j = 0; j < C; ++j) {
          float p = cephes_expf(sval[j] - m);
          cval[j] = p;
          psum += p;
        }
        float cum = 0.f;
        for (int j = 0; j < C; ++j) {
          kept[j] = (j == 0 || cum <= 0.88f) ? 1 : 0;
          cum += cval[j] / psum;
        }
      }
      __syncthreads();

      // gumbel argmax over kept candidates
      float bscore = -INFINITY; int bidx = 0x7FFFFFFF;
      for (int j = tid; j < C; j += 256) {
        if (kept[j]) {
          float gv = gumbel_val(shk0, shk1, b, sidx[j]);
          float sc = gv + sval[j];
          if (sc > bscore || (sc == bscore && sidx[j] < bidx)) { bscore = sc; bidx = sidx[j]; }
        }
      }
      rval[tid] = bscore; ridx[tid] = bidx;
      __syncthreads();
      for (int s = 128; s > 0; s >>= 1) {
        if (tid < s) {
          float ov = rval[tid + s]; int oi = ridx[tid + s];
          if (ov > rval[tid] || (ov == rval[tid] && oi < ridx[tid])) {
            rval[tid] = ov; ridx[tid] = oi;
          }
        }
        __syncthreads();
      }
      if (tid == 0) {
        int tok = ridx[0];
        st_dev(&word[b], tok);
        st_dev(&hist[t * BATCH + b], tok);
        st_dev(&out_tokens[b * MAXT + t], tok);
        atomicAdd(&counts[tok], 1.0f);
      }
      __syncthreads();
    }
    gbar(bar, (++bt) * NB);
  }
}

// ---------------- launcher ----------------
extern "C" void kernel_launch(void* const* d_in, const int* in_sizes, int n_in,
                              void* d_out, int out_size, void* d_ws, size_t ws_size,
                              hipStream_t stream) {
  const float* thought = (const float*)d_in[0];
  const float* emb     = (const float*)d_in[1];
  const float* w_ih0   = (const float*)d_in[2];
  const float* w_hh0   = (const float*)d_in[3];
  const float* b_ih0   = (const float*)d_in[4];
  const float* b_hh0   = (const float*)d_in[5];
  const float* w_ih1   = (const float*)d_in[6];
  const float* w_hh1   = (const float*)d_in[7];
  const float* b_ih1   = (const float*)d_in[8];
  const float* b_hh1   = (const float*)d_in[9];
  const float* gw1     = (const float*)d_in[10];
  const float* gb1     = (const float*)d_in[11];
  const float* gw2     = (const float*)d_in[12];
  const float* gb2     = (const float*)d_in[13];
  const float* out_w   = (const float*)d_in[14];
  const float* out_b   = (const float*)d_in[15];
  int* out_tokens = (int*)d_out;

  float* F = (float*)d_ws;
  float* h1a      = F;
  float* h1b      = F + 65536;
  float* h2a      = F + 131072;
  float* h2b      = F + 196608;
  float* c1       = F + 262144;
  float* c2       = F + 327680;
  float* prev_ctx = F + 393216;
  float* gtmp     = F + 458752;
  float* counts   = F + 524288;
  float* raw      = F + 556288;
  float* adj      = F + 2604288;
  int*   word     = (int*)(F + 4652288);
  int*   hist     = word + 64;
  unsigned* bar   = (unsigned*)(F + 4656448);

  hipMemsetAsync(bar, 0, 64, stream);
  k_mega<<<NB, 256, 0, stream>>>(thought, emb,
      w_ih0, b_ih0, w_hh0, b_hh0, w_ih1, b_ih1, w_hh1, b_hh1,
      gw1, gb1, gw2, gb2, out_w, out_b,
      h1a, h1b, h2a, h2b, c1, c2, prev_ctx, gtmp, counts, raw, adj,
      word, hist, out_tokens, bar);
}